// Round 4
// baseline (492.623 us; speedup 1.0000x reference)
//
#include <hip/hip_runtime.h>
#include <hip/hip_bf16.h>
#include <stdint.h>

#define TOKENS 2048
#define HIDDEN 2048
#define INTER  1408
#define NEXP   8
#define NPAIR  4096

typedef __attribute__((ext_vector_type(8))) short bf16x8;
typedef __attribute__((ext_vector_type(4))) float f32x4;

static __device__ __forceinline__ unsigned short f2b(float f) {
    union { float f; uint32_t u; } v; v.f = f;
    uint32_t r = (v.u + 0x7FFFu + ((v.u >> 16) & 1u)) >> 16;   // RNE
    return (unsigned short)r;
}

// async global->LDS DMA, 16B per lane. Dest must be linear: base + lane*16.
#define GLDS(SRC, DST) \
    __builtin_amdgcn_global_load_lds( \
        (const __attribute__((address_space(1))) unsigned int*)(SRC), \
        (__attribute__((address_space(3))) unsigned int*)(DST), 16, 0, 0)

// ---------------- routing: pack (token, weight) per expert + inverse map ----------------
__global__ void route_k(const int* __restrict__ idx,
                        int* __restrict__ off, int* __restrict__ tok,
                        int* __restrict__ inv) {
    __shared__ int cnt[NEXP];
    __shared__ int cur[NEXP];
    int tid = threadIdx.x;
    if (tid < NEXP) cnt[tid] = 0;
    __syncthreads();
    for (int i = tid; i < NPAIR; i += 256) atomicAdd(&cnt[idx[i]], 1);
    __syncthreads();
    if (tid == 0) {
        int s = 0;
        for (int e = 0; e < NEXP; ++e) { off[e] = s; cur[e] = s; s += cnt[e]; }
        off[NEXP] = s;
    }
    __syncthreads();
    for (int i = tid; i < NPAIR; i += 256) {
        int e = idx[i];
        int p = atomicAdd(&cur[e], 1);
        tok[p] = i >> 1;     // token for packed row p
        inv[i] = p;          // packed row for (token, slot) pair i
    }
}

// ---------------- fp32 -> bf16 bulk convert (X) ----------------
__global__ void conv_k(const float* __restrict__ x, unsigned short* __restrict__ xb, int n) {
    int i = (blockIdx.x * blockDim.x + threadIdx.x) * 4;
    if (i < n) {
        float4 v = *(const float4*)(x + i);
        ushort4 o;
        o.x = f2b(v.x); o.y = f2b(v.y); o.z = f2b(v.z); o.w = f2b(v.w);
        *(ushort4*)(xb + i) = o;
    }
}

// ---------------- fused fp32 -> bf16 convert for the 3 weight tensors ----------------
__global__ void conv3_k(const float* __restrict__ a, unsigned short* __restrict__ ab,
                        const float* __restrict__ b, unsigned short* __restrict__ bb,
                        const float* __restrict__ c, unsigned short* __restrict__ cb,
                        int n4) {
    int stride = gridDim.x * blockDim.x;
    for (int i = blockIdx.x * blockDim.x + threadIdx.x; i < n4; i += stride) {
        int j = i * 4;
        float4 v = *(const float4*)(a + j);
        ushort4 o;
        o.x = f2b(v.x); o.y = f2b(v.y); o.z = f2b(v.z); o.w = f2b(v.w);
        *(ushort4*)(ab + j) = o;
        v = *(const float4*)(b + j);
        o.x = f2b(v.x); o.y = f2b(v.y); o.z = f2b(v.z); o.w = f2b(v.w);
        *(ushort4*)(bb + j) = o;
        v = *(const float4*)(c + j);
        o.x = f2b(v.x); o.y = f2b(v.y); o.z = f2b(v.z); o.w = f2b(v.w);
        *(ushort4*)(cb + j) = o;
    }
}

// ---------------- weighted combine: out[t] = w0*tmp[p0] + w1*tmp[p1] ----------------
__global__ void combine_k(const float* __restrict__ tmp, const int* __restrict__ inv,
                          const float* __restrict__ tw, float* __restrict__ out) {
    int i = blockIdx.x * blockDim.x + threadIdx.x;   // over TOKENS * HIDDEN/4
    int t = i >> 9;                                  // HIDDEN/4 = 512
    int c = (i & 511) * 4;
    int p0 = inv[2 * t], p1 = inv[2 * t + 1];
    float w0 = tw[2 * t], w1 = tw[2 * t + 1];
    float4 x = *(const float4*)(tmp + (size_t)p0 * HIDDEN + c);
    float4 y = *(const float4*)(tmp + (size_t)p1 * HIDDEN + c);
    float4 o;
    o.x = w0 * x.x + w1 * y.x;
    o.y = w0 * x.y + w1 * y.y;
    o.z = w0 * x.z + w1 * y.z;
    o.w = w0 * x.w + w1 * y.w;
    *(float4*)(out + (size_t)t * HIDDEN + c) = o;
}

// LDS row = 32 bf16 elems (64B), 4 slots of 8 elems. Source col pre-swizzled
// (slot q ^= (row>>1)&3) so the linear GLDS write produces a swizzled layout;
// reads XOR the same bits (rule #21). Conflict-free (verified: 0 in R2).

// =================== GEMM1: gate+up fused, SwiGLU -> H (bf16) ===================
// R2 structure (best measured): tile 128x64 dual-output, BK=32, 2-deep,
// 33KB LDS -> 4 blk/CU, stage(b^1,ks+1) -> mfma(b) -> syncthreads.
__global__ __launch_bounds__(256, 4) void gemm1_k(
    const unsigned short* __restrict__ Xb,
    const unsigned short* __restrict__ Wgb, const unsigned short* __restrict__ Wub,
    const int* __restrict__ off, const int* __restrict__ tok,
    unsigned short* __restrict__ H) {

    const int e    = blockIdx.x;
    const int o0   = off[e];
    const int cnt  = off[e + 1] - o0;
    const int row0 = blockIdx.y * 128;
    if (row0 >= cnt) return;
    const int col0 = blockIdx.z * 64;

    __shared__ __align__(16) unsigned short sA[2][128 * 32];
    __shared__ __align__(16) unsigned short sG[2][64 * 32];
    __shared__ __align__(16) unsigned short sU[2][64 * 32];
    __shared__ int stok[128];

    const int tid = threadIdx.x;
    if (tid < 128) {
        int r = row0 + tid;
        stok[tid] = tok[o0 + (r < cnt ? r : cnt - 1)];
    }
    __syncthreads();

    int sa_[2]; const unsigned short* gA[2];
    #pragma unroll
    for (int j = 0; j < 2; ++j) {
        int s = tid + 256 * j, r = s >> 2, q = s & 3;
        sa_[j] = s * 8;
        gA[j] = Xb + (size_t)stok[r] * HIDDEN + ((q ^ ((r >> 1) & 3)) << 3);
    }
    int sb_; const unsigned short* gG; const unsigned short* gU;
    {
        int s = tid, r = s >> 2, q = s & 3;
        sb_ = s * 8;
        int c = (q ^ ((r >> 1) & 3)) << 3;
        gG = Wgb + ((size_t)e * INTER + col0 + r) * HIDDEN + c;
        gU = Wub + ((size_t)e * INTER + col0 + r) * HIDDEN + c;
    }

    const int wave = tid >> 6, lane = tid & 63;
    const int wm = (wave >> 1) * 64, wn = (wave & 1) * 32;
    const int lm = lane & 15, quad = lane >> 4;
    const int swz = ((quad ^ ((lane >> 1) & 3)) << 3);

    f32x4 accg[4][2], accu[4][2];
    #pragma unroll
    for (int i = 0; i < 4; ++i)
        #pragma unroll
        for (int j = 0; j < 2; ++j) {
            accg[i][j] = (f32x4){0.f, 0.f, 0.f, 0.f};
            accu[i][j] = (f32x4){0.f, 0.f, 0.f, 0.f};
        }

    GLDS(gA[0], &sA[0][sa_[0]]);
    GLDS(gA[1], &sA[0][sa_[1]]);
    GLDS(gG, &sG[0][sb_]);
    GLDS(gU, &sU[0][sb_]);
    __syncthreads();

    const int NS = HIDDEN / 32;
    for (int ks = 0; ks < NS; ++ks) {
        const int b = ks & 1;
        if (ks + 1 < NS) {
            const int ko = (ks + 1) * 32;
            GLDS(gA[0] + ko, &sA[b ^ 1][sa_[0]]);
            GLDS(gA[1] + ko, &sA[b ^ 1][sa_[1]]);
            GLDS(gG + ko, &sG[b ^ 1][sb_]);
            GLDS(gU + ko, &sU[b ^ 1][sb_]);
        }
        bf16x8 af[4], gf[2], uf[2];
        #pragma unroll
        for (int mi = 0; mi < 4; ++mi)
            af[mi] = *(const bf16x8*)&sA[b][(wm + mi * 16 + lm) * 32 + swz];
        #pragma unroll
        for (int ni = 0; ni < 2; ++ni) {
            gf[ni] = *(const bf16x8*)&sG[b][(wn + ni * 16 + lm) * 32 + swz];
            uf[ni] = *(const bf16x8*)&sU[b][(wn + ni * 16 + lm) * 32 + swz];
        }
        #pragma unroll
        for (int mi = 0; mi < 4; ++mi)
            #pragma unroll
            for (int ni = 0; ni < 2; ++ni) {
                accg[mi][ni] = __builtin_amdgcn_mfma_f32_16x16x32_bf16(af[mi], gf[ni], accg[mi][ni], 0, 0, 0);
                accu[mi][ni] = __builtin_amdgcn_mfma_f32_16x16x32_bf16(af[mi], uf[ni], accu[mi][ni], 0, 0, 0);
            }
        __syncthreads();
    }

    #pragma unroll
    for (int mi = 0; mi < 4; ++mi) {
        #pragma unroll
        for (int reg = 0; reg < 4; ++reg) {
            int lr = wm + mi * 16 + quad * 4 + reg;   // C/D: col=lane&15, row=quad*4+reg
            int r  = row0 + lr;
            if (r < cnt) {
                size_t hrow = (size_t)(o0 + r) * INTER;
                #pragma unroll
                for (int ni = 0; ni < 2; ++ni) {
                    float g = accg[mi][ni][reg];
                    float u = accu[mi][ni][reg];
                    float h = g / (1.f + __expf(-g)) * u;
                    H[hrow + col0 + wn + ni * 16 + lm] = f2b(h);
                }
            }
        }
    }
}

// =================== GEMM2: down proj -> tmp (plain f32 stores, no atomics) ===================
// tile 128(M) x 128(N), BK=32, 2-deep, 33KB LDS -> 4 blk/CU.
__global__ __launch_bounds__(256, 4) void gemm2_k(
    const unsigned short* __restrict__ H,
    const unsigned short* __restrict__ Wdb,
    const int* __restrict__ off,
    float* __restrict__ tmp) {

    const int e    = blockIdx.x;
    const int o0   = off[e];
    const int cnt  = off[e + 1] - o0;
    const int row0 = blockIdx.y * 128;
    if (row0 >= cnt) return;
    const int col0 = blockIdx.z * 128;

    __shared__ __align__(16) unsigned short sA[2][128 * 32];
    __shared__ __align__(16) unsigned short sB[2][128 * 32];

    const int tid = threadIdx.x;

    int sa_[2];
    const unsigned short* gA[2]; const unsigned short* gB[2];
    #pragma unroll
    for (int j = 0; j < 2; ++j) {
        int s = tid + 256 * j, r = s >> 2, q = s & 3;
        sa_[j] = s * 8;
        int c = (q ^ ((r >> 1) & 3)) << 3;
        int gr = row0 + r; if (gr >= cnt) gr = cnt - 1;
        gA[j] = H + (size_t)(o0 + gr) * INTER + c;
        gB[j] = Wdb + ((size_t)e * HIDDEN + col0 + r) * INTER + c;
    }

    const int wave = tid >> 6, lane = tid & 63;
    const int wm = (wave >> 1) * 64, wn = (wave & 1) * 64;
    const int lm = lane & 15, quad = lane >> 4;
    const int swz = ((quad ^ ((lane >> 1) & 3)) << 3);

    f32x4 acc[4][4];
    #pragma unroll
    for (int i = 0; i < 4; ++i)
        #pragma unroll
        for (int j = 0; j < 4; ++j) acc[i][j] = (f32x4){0.f, 0.f, 0.f, 0.f};

    #pragma unroll
    for (int j = 0; j < 2; ++j) {
        GLDS(gA[j], &sA[0][sa_[j]]);
        GLDS(gB[j], &sB[0][sa_[j]]);
    }
    __syncthreads();

    const int NS = INTER / 32;
    for (int ks = 0; ks < NS; ++ks) {
        const int b = ks & 1;
        if (ks + 1 < NS) {
            const int ko = (ks + 1) * 32;
            #pragma unroll
            for (int j = 0; j < 2; ++j) {
                GLDS(gA[j] + ko, &sA[b ^ 1][sa_[j]]);
                GLDS(gB[j] + ko, &sB[b ^ 1][sa_[j]]);
            }
        }
        bf16x8 af[4], bf[4];
        #pragma unroll
        for (int mi = 0; mi < 4; ++mi)
            af[mi] = *(const bf16x8*)&sA[b][(wm + mi * 16 + lm) * 32 + swz];
        #pragma unroll
        for (int ni = 0; ni < 4; ++ni)
            bf[ni] = *(const bf16x8*)&sB[b][(wn + ni * 16 + lm) * 32 + swz];
        #pragma unroll
        for (int mi = 0; mi < 4; ++mi)
            #pragma unroll
            for (int ni = 0; ni < 4; ++ni)
                acc[mi][ni] = __builtin_amdgcn_mfma_f32_16x16x32_bf16(af[mi], bf[ni], acc[mi][ni], 0, 0, 0);
        __syncthreads();
    }

    #pragma unroll
    for (int mi = 0; mi < 4; ++mi) {
        #pragma unroll
        for (int reg = 0; reg < 4; ++reg) {
            int lr = wm + mi * 16 + quad * 4 + reg;
            int r  = row0 + lr;
            if (r < cnt) {
                size_t trow = (size_t)(o0 + r) * HIDDEN;
                #pragma unroll
                for (int ni = 0; ni < 4; ++ni)
                    tmp[trow + col0 + wn + ni * 16 + lm] = acc[mi][ni][reg];
            }
        }
    }
}

extern "C" void kernel_launch(void* const* d_in, const int* in_sizes, int n_in,
                              void* d_out, int out_size, void* d_ws, size_t ws_size,
                              hipStream_t stream) {
    const float* X   = (const float*)d_in[0];
    const int*   idx = (const int*)d_in[1];
    const float* tw  = (const float*)d_in[2];
    const float* Wg  = (const float*)d_in[3];
    const float* Wu  = (const float*)d_in[4];
    const float* Wd  = (const float*)d_in[5];
    float* out = (float*)d_out;

    char* ws = (char*)d_ws;
    const size_t OFF_TOK = 64;
    const size_t OFF_INV = OFF_TOK + (size_t)NPAIR * 4;
    const size_t OFF_XB  = 65536;
    const size_t OFF_H   = OFF_XB + (size_t)TOKENS * HIDDEN * 2;           // 8 MB Xb
    const size_t WELEMS  = (size_t)NEXP * INTER * HIDDEN;                  // 23.07M
    const size_t OFF_WG  = OFF_H + (size_t)NPAIR * INTER * 2;              // 11.5 MB H
    const size_t OFF_WU  = OFF_WG + WELEMS * 2;
    const size_t OFF_WD  = OFF_WU + WELEMS * 2;
    const size_t OFF_TMP = OFF_WD + WELEMS * 2;                            // 33.5 MB f32

    int*            off = (int*)ws;
    int*            tok = (int*)(ws + OFF_TOK);
    int*            inv = (int*)(ws + OFF_INV);
    unsigned short* Xb  = (unsigned short*)(ws + OFF_XB);
    unsigned short* H   = (unsigned short*)(ws + OFF_H);
    unsigned short* Wgb = (unsigned short*)(ws + OFF_WG);
    unsigned short* Wub = (unsigned short*)(ws + OFF_WU);
    unsigned short* Wdb = (unsigned short*)(ws + OFF_WD);
    float*          tmp = (float*)(ws + OFF_TMP);

    route_k<<<1, 256, 0, stream>>>(idx, off, tok, inv);
    conv_k<<<(TOKENS * HIDDEN / 4 + 255) / 256, 256, 0, stream>>>(X, Xb, TOKENS * HIDDEN);
    conv3_k<<<4096, 256, 0, stream>>>(Wg, Wgb, Wu, Wub, Wd, Wdb, (int)(WELEMS / 4));

    // x = expert: consecutive block IDs spread experts across XCDs (id%8 heuristic);
    // expert's X-tile slice (~2 MB) stays L2-resident on its XCD.
    gemm1_k<<<dim3(NEXP, NPAIR / 128, INTER / 64), 256, 0, stream>>>(Xb, Wgb, Wub, off, tok, H);
    gemm2_k<<<dim3(NEXP, NPAIR / 128, HIDDEN / 128), 256, 0, stream>>>(H, Wdb, off, tmp);
    combine_k<<<TOKENS * (HIDDEN / 4) / 256, 256, 0, stream>>>(tmp, inv, tw, out);
}

// Round 5
// 433.792 us; speedup vs baseline: 1.1356x; 1.1356x over previous
//
#include <hip/hip_runtime.h>
#include <hip/hip_bf16.h>
#include <stdint.h>

#define TOKENS 2048
#define HIDDEN 2048
#define INTER  1408
#define NEXP   8
#define NPAIR  4096

typedef __attribute__((ext_vector_type(8))) short bf16x8;
typedef __attribute__((ext_vector_type(4))) float f32x4;

static __device__ __forceinline__ unsigned short f2b(float f) {
    union { float f; uint32_t u; } v; v.f = f;
    uint32_t r = (v.u + 0x7FFFu + ((v.u >> 16) & 1u)) >> 16;   // RNE
    return (unsigned short)r;
}

// HW RNE pack: two f32 -> one u32 of 2 bf16 (lo in bits 0..15).
static __device__ __forceinline__ uint32_t cvtpk(float lo, float hi) {
    uint32_t r;
    asm("v_cvt_pk_bf16_f32 %0, %1, %2" : "=v"(r) : "v"(lo), "v"(hi));
    return r;
}

// async global->LDS DMA, 16B per lane. Dest must be linear: base + lane*16.
#define GLDS(SRC, DST) \
    __builtin_amdgcn_global_load_lds( \
        (const __attribute__((address_space(1))) unsigned int*)(SRC), \
        (__attribute__((address_space(3))) unsigned int*)(DST), 16, 0, 0)

// ---------------- routing: pack token per expert + inverse map ----------------
__global__ void route_k(const int* __restrict__ idx,
                        int* __restrict__ off, int* __restrict__ tok,
                        int* __restrict__ inv) {
    __shared__ int cnt[NEXP];
    __shared__ int cur[NEXP];
    int tid = threadIdx.x;
    if (tid < NEXP) cnt[tid] = 0;
    __syncthreads();
    for (int i = tid; i < NPAIR; i += 256) atomicAdd(&cnt[idx[i]], 1);
    __syncthreads();
    if (tid == 0) {
        int s = 0;
        for (int e = 0; e < NEXP; ++e) { off[e] = s; cur[e] = s; s += cnt[e]; }
        off[NEXP] = s;
    }
    __syncthreads();
    for (int i = tid; i < NPAIR; i += 256) {
        int e = idx[i];
        int p = atomicAdd(&cur[e], 1);
        tok[p] = i >> 1;     // token for packed row p
        inv[i] = p;          // packed row for (token, slot) pair i
    }
}

// ---------------- fp32 -> bf16 bulk convert (X only; weights stay fp32) ----------------
__global__ void conv_k(const float* __restrict__ x, unsigned short* __restrict__ xb, int n) {
    int i = (blockIdx.x * blockDim.x + threadIdx.x) * 4;
    if (i < n) {
        float4 v = *(const float4*)(x + i);
        ushort4 o;
        o.x = f2b(v.x); o.y = f2b(v.y); o.z = f2b(v.z); o.w = f2b(v.w);
        *(ushort4*)(xb + i) = o;
    }
}

// ---------------- weighted combine: out[t] = w0*tmp[p0] + w1*tmp[p1] ----------------
__global__ void combine_k(const float* __restrict__ tmp, const int* __restrict__ inv,
                          const float* __restrict__ tw, float* __restrict__ out) {
    int i = blockIdx.x * blockDim.x + threadIdx.x;   // over TOKENS * HIDDEN/4
    int t = i >> 9;                                  // HIDDEN/4 = 512
    int c = (i & 511) * 4;
    int p0 = inv[2 * t], p1 = inv[2 * t + 1];
    float w0 = tw[2 * t], w1 = tw[2 * t + 1];
    float4 x = *(const float4*)(tmp + (size_t)p0 * HIDDEN + c);
    float4 y = *(const float4*)(tmp + (size_t)p1 * HIDDEN + c);
    float4 o;
    o.x = w0 * x.x + w1 * y.x;
    o.y = w0 * x.y + w1 * y.y;
    o.z = w0 * x.z + w1 * y.z;
    o.w = w0 * x.w + w1 * y.w;
    *(float4*)(out + (size_t)t * HIDDEN + c) = o;
}

// LDS row = 32 bf16 elems (64B), 4 slots of 8. Content swizzled (slot q ^=
// (row>>1)&3) applied on the SOURCE column; dest stays linear (rule #21).
// Reads XOR the same bits. Conflict-free (verified: 0 since R2).
// Weights are read fp32 from HBM and converted in-flight: loads issued at
// step top, cvt_pk + ds_write after the MFMA section (T14 split) -> latency
// hides under compute; __syncthreads drains both GLDS and ds_write.

// =================== GEMM1: gate+up fused, SwiGLU -> H (bf16) ===================
// tile 128(M) x 64(N) dual-output, BK=32, 2-deep, 32.5KB LDS -> 4 blk/CU.
__global__ __launch_bounds__(256, 4) void gemm1_k(
    const unsigned short* __restrict__ Xb,
    const float* __restrict__ Wg, const float* __restrict__ Wu,
    const int* __restrict__ off, const int* __restrict__ tok,
    unsigned short* __restrict__ H) {

    const int e    = blockIdx.z;
    const int o0   = off[e];
    const int cnt  = off[e + 1] - o0;
    const int row0 = blockIdx.y * 128;
    if (row0 >= cnt) return;
    const int col0 = blockIdx.x * 64;

    __shared__ __align__(16) unsigned short sA[2][128 * 32];
    __shared__ __align__(16) unsigned short sG[2][64 * 32];
    __shared__ __align__(16) unsigned short sU[2][64 * 32];
    __shared__ int stok[128];

    const int tid = threadIdx.x;
    if (tid < 128) {
        int r = row0 + tid;
        stok[tid] = tok[o0 + (r < cnt ? r : cnt - 1)];
    }
    __syncthreads();

    // A: 2 segs/thread via GLDS (bf16 source).
    int sa_[2]; const unsigned short* gA[2];
    #pragma unroll
    for (int j = 0; j < 2; ++j) {
        int s = tid + 256 * j, r = s >> 2, q = s & 3;
        sa_[j] = s * 8;
        gA[j] = Xb + (size_t)stok[r] * HIDDEN + ((q ^ ((r >> 1) & 3)) << 3);
    }
    // G,U: 8 fp32/thread, reg-staged + converted.
    int sb_; const float* fG; const float* fU;
    {
        int s = tid, r = s >> 2, q = s & 3;
        sb_ = s * 8;
        int c = (q ^ ((r >> 1) & 3)) << 3;
        fG = Wg + ((size_t)e * INTER + col0 + r) * HIDDEN + c;
        fU = Wu + ((size_t)e * INTER + col0 + r) * HIDDEN + c;
    }

    const int wave = tid >> 6, lane = tid & 63;
    const int wm = (wave >> 1) * 64, wn = (wave & 1) * 32;
    const int lm = lane & 15, quad = lane >> 4;
    const int swz = ((quad ^ ((lane >> 1) & 3)) << 3);

    f32x4 accg[4][2], accu[4][2];
    #pragma unroll
    for (int i = 0; i < 4; ++i)
        #pragma unroll
        for (int j = 0; j < 2; ++j) {
            accg[i][j] = (f32x4){0.f, 0.f, 0.f, 0.f};
            accu[i][j] = (f32x4){0.f, 0.f, 0.f, 0.f};
        }

    // prologue: slice 0 into buf 0
    GLDS(gA[0], &sA[0][sa_[0]]);
    GLDS(gA[1], &sA[0][sa_[1]]);
    {
        float4 g0 = *(const float4*)(fG);
        float4 g1 = *(const float4*)(fG + 4);
        float4 u0 = *(const float4*)(fU);
        float4 u1 = *(const float4*)(fU + 4);
        *(int4*)&sG[0][sb_] = make_int4(cvtpk(g0.x, g0.y), cvtpk(g0.z, g0.w),
                                        cvtpk(g1.x, g1.y), cvtpk(g1.z, g1.w));
        *(int4*)&sU[0][sb_] = make_int4(cvtpk(u0.x, u0.y), cvtpk(u0.z, u0.w),
                                        cvtpk(u1.x, u1.y), cvtpk(u1.z, u1.w));
    }
    __syncthreads();

    const int NS = HIDDEN / 32;
    for (int ks = 0; ks < NS; ++ks) {
        const int b = ks & 1;
        float4 g0, g1, u0, u1;
        if (ks + 1 < NS) {              // issue next-slice loads before compute
            const int ko = (ks + 1) * 32;
            GLDS(gA[0] + ko, &sA[b ^ 1][sa_[0]]);
            GLDS(gA[1] + ko, &sA[b ^ 1][sa_[1]]);
            g0 = *(const float4*)(fG + ko);
            g1 = *(const float4*)(fG + ko + 4);
            u0 = *(const float4*)(fU + ko);
            u1 = *(const float4*)(fU + ko + 4);
        }
        bf16x8 af[4], gf[2], uf[2];
        #pragma unroll
        for (int mi = 0; mi < 4; ++mi)
            af[mi] = *(const bf16x8*)&sA[b][(wm + mi * 16 + lm) * 32 + swz];
        #pragma unroll
        for (int ni = 0; ni < 2; ++ni) {
            gf[ni] = *(const bf16x8*)&sG[b][(wn + ni * 16 + lm) * 32 + swz];
            uf[ni] = *(const bf16x8*)&sU[b][(wn + ni * 16 + lm) * 32 + swz];
        }
        #pragma unroll
        for (int mi = 0; mi < 4; ++mi)
            #pragma unroll
            for (int ni = 0; ni < 2; ++ni) {
                accg[mi][ni] = __builtin_amdgcn_mfma_f32_16x16x32_bf16(af[mi], gf[ni], accg[mi][ni], 0, 0, 0);
                accu[mi][ni] = __builtin_amdgcn_mfma_f32_16x16x32_bf16(af[mi], uf[ni], accu[mi][ni], 0, 0, 0);
            }
        if (ks + 1 < NS) {              // cvt + write late: loads landed under MFMA
            *(int4*)&sG[b ^ 1][sb_] = make_int4(cvtpk(g0.x, g0.y), cvtpk(g0.z, g0.w),
                                                cvtpk(g1.x, g1.y), cvtpk(g1.z, g1.w));
            *(int4*)&sU[b ^ 1][sb_] = make_int4(cvtpk(u0.x, u0.y), cvtpk(u0.z, u0.w),
                                                cvtpk(u1.x, u1.y), cvtpk(u1.z, u1.w));
        }
        __syncthreads();                // drains GLDS + ds_write for buf b^1
    }

    #pragma unroll
    for (int mi = 0; mi < 4; ++mi) {
        #pragma unroll
        for (int reg = 0; reg < 4; ++reg) {
            int lr = wm + mi * 16 + quad * 4 + reg;   // C/D: col=lane&15, row=quad*4+reg
            int r  = row0 + lr;
            if (r < cnt) {
                size_t hrow = (size_t)(o0 + r) * INTER;
                #pragma unroll
                for (int ni = 0; ni < 2; ++ni) {
                    float g = accg[mi][ni][reg];
                    float u = accu[mi][ni][reg];
                    float h = g / (1.f + __expf(-g)) * u;
                    H[hrow + col0 + wn + ni * 16 + lm] = f2b(h);
                }
            }
        }
    }
}

// =================== GEMM2: down proj -> tmp (plain f32 stores) ===================
// tile 128(M) x 64(N), BK=32, 2-deep, 24.5KB LDS; 1024 active blocks = 100% fill.
__global__ __launch_bounds__(256, 4) void gemm2_k(
    const unsigned short* __restrict__ H,
    const float* __restrict__ Wd,
    const int* __restrict__ off,
    float* __restrict__ tmp) {

    const int e    = blockIdx.z;
    const int o0   = off[e];
    const int cnt  = off[e + 1] - o0;
    const int row0 = blockIdx.y * 128;
    if (row0 >= cnt) return;
    const int col0 = blockIdx.x * 64;

    __shared__ __align__(16) unsigned short sA[2][128 * 32];
    __shared__ __align__(16) unsigned short sB[2][64 * 32];

    const int tid = threadIdx.x;

    int sa_[2]; const unsigned short* gA[2];
    #pragma unroll
    for (int j = 0; j < 2; ++j) {
        int s = tid + 256 * j, r = s >> 2, q = s & 3;
        sa_[j] = s * 8;
        int c = (q ^ ((r >> 1) & 3)) << 3;
        int gr = row0 + r; if (gr >= cnt) gr = cnt - 1;
        gA[j] = H + (size_t)(o0 + gr) * INTER + c;
    }
    int sb_; const float* fB;
    {
        int s = tid, r = s >> 2, q = s & 3;
        sb_ = s * 8;
        int c = (q ^ ((r >> 1) & 3)) << 3;
        fB = Wd + ((size_t)e * HIDDEN + col0 + r) * INTER + c;
    }

    const int wave = tid >> 6, lane = tid & 63;
    const int wm = (wave >> 1) * 64, wn = (wave & 1) * 32;
    const int lm = lane & 15, quad = lane >> 4;
    const int swz = ((quad ^ ((lane >> 1) & 3)) << 3);

    f32x4 acc[4][2];
    #pragma unroll
    for (int i = 0; i < 4; ++i)
        #pragma unroll
        for (int j = 0; j < 2; ++j) acc[i][j] = (f32x4){0.f, 0.f, 0.f, 0.f};

    // prologue
    GLDS(gA[0], &sA[0][sa_[0]]);
    GLDS(gA[1], &sA[0][sa_[1]]);
    {
        float4 b0 = *(const float4*)(fB);
        float4 b1 = *(const float4*)(fB + 4);
        *(int4*)&sB[0][sb_] = make_int4(cvtpk(b0.x, b0.y), cvtpk(b0.z, b0.w),
                                        cvtpk(b1.x, b1.y), cvtpk(b1.z, b1.w));
    }
    __syncthreads();

    const int NS = INTER / 32;
    for (int ks = 0; ks < NS; ++ks) {
        const int b = ks & 1;
        float4 b0, b1;
        if (ks + 1 < NS) {
            const int ko = (ks + 1) * 32;
            GLDS(gA[0] + ko, &sA[b ^ 1][sa_[0]]);
            GLDS(gA[1] + ko, &sA[b ^ 1][sa_[1]]);
            b0 = *(const float4*)(fB + ko);
            b1 = *(const float4*)(fB + ko + 4);
        }
        bf16x8 af[4], bf[2];
        #pragma unroll
        for (int mi = 0; mi < 4; ++mi)
            af[mi] = *(const bf16x8*)&sA[b][(wm + mi * 16 + lm) * 32 + swz];
        #pragma unroll
        for (int ni = 0; ni < 2; ++ni)
            bf[ni] = *(const bf16x8*)&sB[b][(wn + ni * 16 + lm) * 32 + swz];
        #pragma unroll
        for (int mi = 0; mi < 4; ++mi)
            #pragma unroll
            for (int ni = 0; ni < 2; ++ni)
                acc[mi][ni] = __builtin_amdgcn_mfma_f32_16x16x32_bf16(af[mi], bf[ni], acc[mi][ni], 0, 0, 0);
        if (ks + 1 < NS) {
            *(int4*)&sB[b ^ 1][sb_] = make_int4(cvtpk(b0.x, b0.y), cvtpk(b0.z, b0.w),
                                                cvtpk(b1.x, b1.y), cvtpk(b1.z, b1.w));
        }
        __syncthreads();
    }

    #pragma unroll
    for (int mi = 0; mi < 4; ++mi) {
        #pragma unroll
        for (int reg = 0; reg < 4; ++reg) {
            int lr = wm + mi * 16 + quad * 4 + reg;
            int r  = row0 + lr;
            if (r < cnt) {
                size_t trow = (size_t)(o0 + r) * HIDDEN;
                #pragma unroll
                for (int ni = 0; ni < 2; ++ni)
                    tmp[trow + col0 + wn + ni * 16 + lm] = acc[mi][ni][reg];
            }
        }
    }
}

extern "C" void kernel_launch(void* const* d_in, const int* in_sizes, int n_in,
                              void* d_out, int out_size, void* d_ws, size_t ws_size,
                              hipStream_t stream) {
    const float* X   = (const float*)d_in[0];
    const int*   idx = (const int*)d_in[1];
    const float* tw  = (const float*)d_in[2];
    const float* Wg  = (const float*)d_in[3];
    const float* Wu  = (const float*)d_in[4];
    const float* Wd  = (const float*)d_in[5];
    float* out = (float*)d_out;

    char* ws = (char*)d_ws;
    const size_t OFF_TOK = 64;
    const size_t OFF_INV = OFF_TOK + (size_t)NPAIR * 4;
    const size_t OFF_XB  = 65536;
    const size_t OFF_H   = OFF_XB + (size_t)TOKENS * HIDDEN * 2;           // 8 MB Xb
    const size_t OFF_TMP = OFF_H + (size_t)NPAIR * INTER * 2;              // 11.5 MB H

    int*            off = (int*)ws;
    int*            tok = (int*)(ws + OFF_TOK);
    int*            inv = (int*)(ws + OFF_INV);
    unsigned short* Xb  = (unsigned short*)(ws + OFF_XB);
    unsigned short* H   = (unsigned short*)(ws + OFF_H);
    float*          tmp = (float*)(ws + OFF_TMP);                          // 33.5 MB f32

    route_k<<<1, 256, 0, stream>>>(idx, off, tok, inv);
    conv_k<<<(TOKENS * HIDDEN / 4 + 255) / 256, 256, 0, stream>>>(X, Xb, TOKENS * HIDDEN);

    // grid: x=colTile (fastest) -> XCDs get a balanced mix of experts/tiles.
    gemm1_k<<<dim3(INTER / 64, NPAIR / 128, NEXP), 256, 0, stream>>>(Xb, Wg, Wu, off, tok, H);
    gemm2_k<<<dim3(HIDDEN / 64, NPAIR / 128, NEXP), 256, 0, stream>>>(H, Wd, off, tmp);
    combine_k<<<TOKENS * (HIDDEN / 4) / 256, 256, 0, stream>>>(tmp, inv, tw, out);
}